// Round 20
// baseline (426.601 us; speedup 1.0000x reference)
//
#include <hip/hip_runtime.h>
#include <hip/hip_bf16.h>

typedef __bf16 bf16_t;
typedef __bf16 bf16x4 __attribute__((ext_vector_type(4)));
typedef __bf16 bf16x8 __attribute__((ext_vector_type(8)));
typedef float  f32x4  __attribute__((ext_vector_type(4)));

#define NH    6
#define CH    192
#define HW    112
#define SHIFT 3

#define XLD 200   // X / T row stride (400B rows, b128-aligned)
#define PLD 68    // P row stride (136B rows)

// LDS map (elems). No overlays. X rows 49-63 don't exist: reads past row 48
// land in T0/T1/P (in-allocation garbage) and are masked everywhere.
#define X_OFF   0        // [49][200] = 9800
#define T0_OFF  9800     // [49][200] = 9800
#define T1_OFF  19600    // [49][200] = 9800
#define P0_OFF  29400    // [64][68]  = 4352
#define P1_OFF  33752    // [64][68]  = 4352
#define LDS_ELEMS 38104
#define LDS_BYTES (LDS_ELEMS * 2)   // 76208 B -> 2 blocks/CU

// ws: Gt swizzled (NH*CH*CH bf16) | U swizzled (NH*CH*CH bf16) | bu | w1
// Swizzled fragment layout: [h][tile(12)][ks(6)][lane(64)][e(8)] -> one wave
// A-fragment load = contiguous 1024 B.
#define U_OFF_ELEMS  (NH * CH * CH)
#define BU_OFF_BYTES (2 * NH * CH * CH * 2)
#define W1_OFF_BYTES (BU_OFF_BYTES + NH * CH * 4)

// ---- fused prep: one kernel, block ranges do {Gt | U | bu+w1} --------------
//   Gt[h][c'][c] = sum_d Wk[c',h,d] Wq[c,h,d]   (blocks 0 .. NH*CH-1)
//   U[h][cout][cin] = sum_d Wv[cin,h,d] Wo[h,d,cout] (blocks NH*CH .. 2*NH*CH-1)
//   bu[h][c] = sum_d bv[h,d] Wo[h,d,c]; w1[h][c'] = sum_d Wk[c',h,d] bq[h,d]
//   (block 2*NH*CH)
__global__ void prep_all(const float* __restrict__ Wq, const float* __restrict__ bq,
                         const float* __restrict__ Wk, const float* __restrict__ Wv,
                         const float* __restrict__ Wo, const float* __restrict__ bv,
                         bf16_t* __restrict__ wts, float* __restrict__ bu,
                         float* __restrict__ w1) {
  __shared__ float srow[CH];
  const int bid = blockIdx.x;
  const int t = threadIdx.x;
  if (bid < NH * CH) {                       // ---- Gt, swizzled
    int h = bid / CH, cp = bid % CH;
    srow[t] = Wk[(cp * NH + h) * CH + t];
    __syncthreads();
    float acc = 0.f;
    for (int d = 0; d < CH; ++d)
      acc += srow[d] * Wq[(t * NH + h) * CH + d];
    int tile = cp >> 4, l15 = cp & 15;
    int ks = t >> 5, lg = (t >> 3) & 3, e = t & 7;
    wts[((((h * 12 + tile) * 6 + ks) << 6) + lg * 16 + l15) * 8 + e] = (bf16_t)acc;
  } else if (bid < 2 * NH * CH) {            // ---- U = Wv x Wo, swizzled
    int r = bid - NH * CH;
    int h = r / CH, ci = r % CH;
    srow[t] = Wv[(ci * NH + h) * CH + t];
    __syncthreads();
    float acc = 0.f;
    for (int d = 0; d < CH; ++d)
      acc += srow[d] * Wo[(h * CH + d) * CH + t];
    int tile = t >> 4, l15 = t & 15;
    int ks = ci >> 5, lg = (ci >> 3) & 3, e = ci & 7;
    wts[U_OFF_ELEMS + ((((h * 12 + tile) * 6 + ks) << 6) + lg * 16 + l15) * 8 + e] = (bf16_t)acc;
  } else {                                   // ---- bu + w1 (all heads, 1 block)
    for (int h = 0; h < NH; ++h) {
      float accb = 0.f, accw = 0.f;
      for (int d = 0; d < CH; ++d) {
        accb += bv[h * CH + d] * Wo[(h * CH + d) * CH + t];
        accw += Wk[(t * NH + h) * CH + d] * bq[h * CH + d];
      }
      bu[h * CH + t] = accb;
      w1[h * CH + t] = accw;
    }
  }
}

// ---- T phase: T[i][c'] = sum_c X[i,c] Gt[c',c] (+w1), 2 i-half passes ------
__device__ __forceinline__ void t_phase(const bf16_t* __restrict__ gt,
                                        const float* __restrict__ w1h,
                                        const bf16_t* Xl, bf16_t* Tdst,
                                        int hh, int wm, int lane, int l15, int lg) {
  f32x4 ww[3];
#pragma unroll
  for (int mi = 0; mi < 3; ++mi)
    ww[mi] = *(const f32x4*)&w1h[(wm + mi) * 16 + lg * 4];
#pragma unroll
  for (int ip = 0; ip < 2; ++ip) {
    f32x4 acc[3][2];
#pragma unroll
    for (int mi = 0; mi < 3; ++mi)
#pragma unroll
      for (int n2 = 0; n2 < 2; ++n2) acc[mi][n2] = ww[mi];
#pragma unroll
    for (int ks = 0; ks < 6; ++ks) {
      bf16x8 af[3], bfr[2];
#pragma unroll
      for (int mi = 0; mi < 3; ++mi)
        af[mi] = *(const bf16x8*)&gt[((((hh * 12 + wm + mi) * 6 + ks) << 6) + lane) * 8];
#pragma unroll
      for (int n2 = 0; n2 < 2; ++n2)
        bfr[n2] = *(const bf16x8*)&Xl[((ip * 2 + n2) * 16 + l15) * XLD + ks * 32 + lg * 8];
#pragma unroll
      for (int mi = 0; mi < 3; ++mi)
#pragma unroll
        for (int n2 = 0; n2 < 2; ++n2)
          acc[mi][n2] = __builtin_amdgcn_mfma_f32_16x16x32_bf16(af[mi], bfr[n2], acc[mi][n2], 0, 0, 0);
    }
#pragma unroll
    for (int mi = 0; mi < 3; ++mi) {
      int cp0 = (wm + mi) * 16 + lg * 4;
#pragma unroll
      for (int n2 = 0; n2 < 2; ++n2) {
        int i = (ip * 2 + n2) * 16 + l15;
        if (i < 49) {
          bf16x4 pk = { (bf16_t)acc[mi][n2][0], (bf16_t)acc[mi][n2][1],
                        (bf16_t)acc[mi][n2][2], (bf16_t)acc[mi][n2][3] };
          *(bf16x4*)&Tdst[i * XLD + cp0] = pk;
        }
      }
    }
  }
}

// ---- fused swin block: one 4-wave workgroup per window, 1 barrier/head -----
__global__ __launch_bounds__(256, 2) void swin_fused(
    const float* __restrict__ x,
    const float* __restrict__ bo,
    const bf16_t* __restrict__ wts,     // Gt | U (both swizzled)
    const float* __restrict__ bu, const float* __restrict__ w1,
    float* __restrict__ out) {
  extern __shared__ char smem_raw[];
  bf16_t* lds = (bf16_t*)smem_raw;
  bf16_t* Xl  = lds + X_OFF;

  const int tid  = threadIdx.x;
  const int wave = tid >> 6;           // 0..3  (owns i-tile `wave`)
  const int lane = tid & 63;
  const int l15  = lane & 15;
  const int lg   = lane >> 4;          // 0..3

  const int blk = blockIdx.x;
  const int b   = blk >> 8;
  const int rem = blk & 255;
  const int wi  = rem >> 4, wj = rem & 15;

  // stage window tokens (roll -3,-3 folded into the gather), f32 -> bf16.
  // Only rows < 49 exist; all consumers mask/guard rows >= 49.
  for (int idx = tid; idx < 49 * 48; idx += 256) {
    int t = idx / 48, q4 = idx % 48;
    int hs = wi * 7 + t / 7 + SHIFT; if (hs >= HW) hs -= HW;
    int ws2 = wj * 7 + t % 7 + SHIFT; if (ws2 >= HW) ws2 -= HW;
    const float4 v = *(const float4*)&x[(((b * HW + hs) * HW) + ws2) * CH + q4 * 4];
    bf16x4 pk = { (bf16_t)v.x, (bf16_t)v.y, (bf16_t)v.z, (bf16_t)v.w };
    *(bf16x4*)&Xl[t * XLD + q4 * 4] = pk;
  }
  __syncthreads();   // X ready

  const int wm = wave * 3;             // 3 c'/c-tiles owned per wave
  const float scale = 0.07216878364870322f;  // 1/sqrt(192)

  // prologue: T(0) -> T0
  t_phase(wts, w1, Xl, lds + T0_OFF, 0, wm, lane, l15, lg);
  __syncthreads();   // T(0) ready

  f32x4 yacc[3][4] = {};               // lane: Y[t=ni*16+lg*4+r][c=(wm+mi)*16+l15]

  for (int h = 0; h < NH; ++h) {
    const bf16_t* Tcur = lds + ((h & 1) ? T1_OFF : T0_OFF);
    bf16_t*       Pcur = lds + ((h & 1) ? P1_OFF : P0_OFF);

    // ---- S(h): S[i = wave-tile, j] = sum_c' X[j,c'] T[i,c'].
    // Softmax WITHOUT max-pass: scores are tiny by construction (|s*scale|
    // std ~0.08, exp in [0.7,1.4]) -> P = e_j / sum e_j exactly.
    bf16x4 psave[4];
    {
      f32x4 sacc[4] = {};
#pragma unroll
      for (int ks = 0; ks < 6; ++ks) {
        bf16x8 bt = *(const bf16x8*)&Tcur[(wave * 16 + l15) * XLD + ks * 32 + lg * 8];
#pragma unroll
        for (int mj = 0; mj < 4; ++mj) {
          bf16x8 af = *(const bf16x8*)&Xl[(mj * 16 + l15) * XLD + ks * 32 + lg * 8];
          sacc[mj] = __builtin_amdgcn_mfma_f32_16x16x32_bf16(af, bt, sacc[mj], 0, 0, 0);
        }
      }
      float p[4][4];
      float sum = 0.f;
#pragma unroll
      for (int mj = 0; mj < 3; ++mj)
#pragma unroll
        for (int r = 0; r < 4; ++r) {
          float e = __expf(sacc[mj][r] * scale);
          p[mj][r] = e;
          sum += e;
        }
      {  // mj==3: only j==48 (lg==0, r==0) is a real row
        float e0 = (lg == 0) ? __expf(sacc[3][0] * scale) : 0.f;
        p[3][0] = e0; p[3][1] = 0.f; p[3][2] = 0.f; p[3][3] = 0.f;
        sum += e0;
      }
      sum += __shfl_xor(sum, 16);
      sum += __shfl_xor(sum, 32);
      float inv = 1.f / sum;
#pragma unroll
      for (int mj = 0; mj < 4; ++mj) {
        bf16x4 pk = { (bf16_t)(p[mj][0] * inv), (bf16_t)(p[mj][1] * inv),
                      (bf16_t)(p[mj][2] * inv), (bf16_t)(p[mj][3] * inv) };
        psave[mj] = pk;
      }
    }
    // ---- P-write(h): P[i][j] rows into Pcur (read by Y after the barrier)
    {
      int irow = wave * 16 + l15;
#pragma unroll
      for (int mj = 0; mj < 4; ++mj)
        *(bf16x4*)&Pcur[irow * PLD + mj * 16 + lg * 4] = psave[mj];
    }
    // ---- T(h+1) into the other T buffer (hazard-free: S read Tcur, B1 ahead)
    if (h + 1 < NH)
      t_phase(wts, w1 + (h + 1) * CH, Xl, lds + (((h + 1) & 1) ? T1_OFF : T0_OFF),
              h + 1, wm, lane, l15, lg);
    // ---- VO(h): VO[c][s] = sum_cin X[s,cin] U[c,cin] (+bu), kept in regs.
    // Per-mi pass; vacc lane layout (c = l15 fixed, s in regs) IS the Y B-frag.
    bf16x8 bfrag[3][2];
    {
      const bf16_t* U_w = wts + U_OFF_ELEMS;
      const float* bu_h = bu + h * CH;
#pragma unroll
      for (int mi = 0; mi < 3; ++mi) {
        const f32x4 bbv = *(const f32x4*)&bu_h[(wm + mi) * 16 + lg * 4];
        f32x4 vacc[4];
#pragma unroll
        for (int ms = 0; ms < 4; ++ms) vacc[ms] = bbv;
#pragma unroll
        for (int ks = 0; ks < 6; ++ks) {
          bf16x8 bfu = *(const bf16x8*)&U_w[((((h * 12 + wm + mi) * 6 + ks) << 6) + lane) * 8];
#pragma unroll
          for (int ms = 0; ms < 4; ++ms) {
            bf16x8 af = *(const bf16x8*)&Xl[(ms * 16 + l15) * XLD + ks * 32 + lg * 8];
            vacc[ms] = __builtin_amdgcn_mfma_f32_16x16x32_bf16(af, bfu, vacc[ms], 0, 0, 0);
          }
        }
        // zero garbage s >= 49 slots (X rows 49-63 are unstaged garbage)
        if (lg) { vacc[3] = (f32x4){0.f, 0.f, 0.f, 0.f}; }
        else    { vacc[3][1] = 0.f; vacc[3][2] = 0.f; vacc[3][3] = 0.f; }
#pragma unroll
        for (int kp = 0; kp < 2; ++kp) {
          bf16x4 lo = { (bf16_t)vacc[2 * kp][0], (bf16_t)vacc[2 * kp][1],
                        (bf16_t)vacc[2 * kp][2], (bf16_t)vacc[2 * kp][3] };
          bf16x4 hi = { (bf16_t)vacc[2 * kp + 1][0], (bf16_t)vacc[2 * kp + 1][1],
                        (bf16_t)vacc[2 * kp + 1][2], (bf16_t)vacc[2 * kp + 1][3] };
          bfrag[mi][kp] = __builtin_shufflevector(lo, hi, 0, 1, 2, 3, 4, 5, 6, 7);
        }
      }
    }
    __syncthreads();   // B1(h): all waves' P(h) and T(h+1) written
    // ---- Y(h): Y[t][c] += sum_s P[t,s] VO[c,s].
    // A = P rows (permuted b64 pair, k~ = s); B = bfrag (same permutation).
    {
#pragma unroll
      for (int ni = 0; ni < 4; ++ni) {
#pragma unroll
        for (int kp = 0; kp < 2; ++kp) {
          const bf16_t* pr = &Pcur[(ni * 16 + l15) * PLD + kp * 32 + lg * 4];
          bf16x4 a0 = *(const bf16x4*)pr;
          bf16x4 a1 = *(const bf16x4*)(pr + 16);
          bf16x8 af8 = __builtin_shufflevector(a0, a1, 0, 1, 2, 3, 4, 5, 6, 7);
#pragma unroll
          for (int mi = 0; mi < 3; ++mi)
            yacc[mi][ni] = __builtin_amdgcn_mfma_f32_16x16x32_bf16(af8, bfrag[mi][kp], yacc[mi][ni], 0, 0, 0);
        }
      }
    }
    // no trailing barrier: next iteration's writes touch only the other
    // T/P buffers; all cross-buffer hazards were separated by B1(h).
  }

  // ---- epilogue: +bo, plain-reshape merge + roll(+3,+3), scalar f32 stores
  {
    float bov[3];
#pragma unroll
    for (int mi = 0; mi < 3; ++mi) bov[mi] = bo[(wm + mi) * 16 + l15];
#pragma unroll
    for (int ni = 0; ni < 4; ++ni) {
#pragma unroll
      for (int r = 0; r < 4; ++r) {
        int t = ni * 16 + lg * 4 + r;
        if (t < 49) {
          int pos = rem * 49 + t;
          int hp = pos / 112, wp = pos % 112;
          hp += SHIFT; if (hp >= HW) hp -= HW;
          wp += SHIFT; if (wp >= HW) wp -= HW;
          float* op = out + (((b * HW + hp) * HW) + wp) * CH + l15;
#pragma unroll
          for (int mi = 0; mi < 3; ++mi)
            op[(wm + mi) * 16] = yacc[mi][ni][r] + bov[mi];
        }
      }
    }
  }
}

extern "C" void kernel_launch(void* const* d_in, const int* in_sizes, int n_in,
                              void* d_out, int out_size, void* d_ws, size_t ws_size,
                              hipStream_t stream) {
  const float* x  = (const float*)d_in[0];
  const float* Wq = (const float*)d_in[1];
  const float* bq = (const float*)d_in[2];
  const float* Wk = (const float*)d_in[3];
  const float* Wv = (const float*)d_in[5];
  const float* bv = (const float*)d_in[6];
  const float* Wo = (const float*)d_in[7];
  const float* bo = (const float*)d_in[8];
  float* out = (float*)d_out;
  bf16_t* wts = (bf16_t*)d_ws;                        // Gt | U, swizzled
  float*  bu  = (float*)((char*)d_ws + BU_OFF_BYTES);
  float*  w1  = (float*)((char*)d_ws + W1_OFF_BYTES);

  prep_all<<<2 * NH * CH + 1, CH, 0, stream>>>(Wq, bq, Wk, Wv, Wo, bv, wts, bu, w1);

  (void)hipFuncSetAttribute((const void*)swin_fused,
                            hipFuncAttributeMaxDynamicSharedMemorySize, LDS_BYTES);
  swin_fused<<<dim3(4096), dim3(256), LDS_BYTES, stream>>>(x, bo, wts, bu, w1, out);
}

// Round 21
// 401.694 us; speedup vs baseline: 1.0620x; 1.0620x over previous
//
#include <hip/hip_runtime.h>
#include <hip/hip_bf16.h>

typedef __bf16 bf16_t;
typedef __bf16 bf16x4 __attribute__((ext_vector_type(4)));
typedef __bf16 bf16x8 __attribute__((ext_vector_type(8)));
typedef float  f32x4  __attribute__((ext_vector_type(4)));

#define NH    6
#define CH    192
#define HW    112
#define SHIFT 3

#define XLD 200   // X / T row stride (400B rows, b128-aligned)
#define PLD 68    // P row stride (136B rows)

// LDS map (elems). No overlays. X rows 49-63 don't exist: reads past row 48
// land in T0/T1/P (in-allocation garbage) and are masked everywhere.
#define X_OFF   0        // [49][200] = 9800
#define T0_OFF  9800     // [49][200] = 9800
#define T1_OFF  19600    // [49][200] = 9800
#define P0_OFF  29400    // [64][68]  = 4352
#define P1_OFF  33752    // [64][68]  = 4352
#define LDS_ELEMS 38104
#define LDS_BYTES (LDS_ELEMS * 2)   // 76208 B -> 2 blocks/CU

// ws: Gt swizzled (NH*CH*CH bf16) | U swizzled (NH*CH*CH bf16) | bu | w1
// Swizzled fragment layout: [h][tile(12)][ks(6)][lane(64)][e(8)] -> one wave
// A-fragment load = contiguous 1024 B.
#define U_OFF_ELEMS  (NH * CH * CH)
#define BU_OFF_BYTES (2 * NH * CH * CH * 2)
#define W1_OFF_BYTES (BU_OFF_BYTES + NH * CH * 4)

// ---- prep: Gt[h][c'][c] = sum_d Wk[c',h,d] * Wq[c,h,d], written SWIZZLED ---
__global__ void prep_gt(const float* __restrict__ Wq, const float* __restrict__ Wk,
                        bf16_t* __restrict__ gt) {
  __shared__ float wk_row[CH];
  int h = blockIdx.x / CH, cp = blockIdx.x % CH;
  int c = threadIdx.x;
  wk_row[c] = Wk[(cp * NH + h) * CH + c];
  __syncthreads();
  float acc = 0.f;
  for (int d = 0; d < CH; ++d)
    acc += wk_row[d] * Wq[(c * NH + h) * CH + d];
  int tile = cp >> 4, l15 = cp & 15;
  int ks = c >> 5, lg = (c >> 3) & 3, e = c & 7;
  gt[((((h * 12 + tile) * 6 + ks) << 6) + lg * 16 + l15) * 8 + e] = (bf16_t)acc;
}

// ---- prep: U^h = Wv^h x Wo^h, rows c_out, cols c_in, written SWIZZLED ------
__global__ void prep_u(const float* __restrict__ Wv, const float* __restrict__ Wo,
                       bf16_t* __restrict__ u_out) {
  __shared__ float wv_row[CH];
  int h = blockIdx.x / CH, ci = blockIdx.x % CH;
  int t = threadIdx.x;                            // c_out
  wv_row[t] = Wv[(ci * NH + h) * CH + t];
  __syncthreads();
  float acc = 0.f;
  for (int d = 0; d < CH; ++d)
    acc += wv_row[d] * Wo[(h * CH + d) * CH + t];
  int tile = t >> 4, l15 = t & 15;
  int ks = ci >> 5, lg = (ci >> 3) & 3, e = ci & 7;
  u_out[((((h * 12 + tile) * 6 + ks) << 6) + lg * 16 + l15) * 8 + e] = (bf16_t)acc;
}

// ---- prep: bu^h = bv^h x Wo^h ---------------------------------------------
__global__ void prep_bu(const float* __restrict__ bv, const float* __restrict__ Wo,
                        float* __restrict__ bu) {
  int h = blockIdx.x, c = threadIdx.x;
  float acc = 0.f;
  for (int d = 0; d < CH; ++d)
    acc += bv[h * CH + d] * Wo[(h * CH + d) * CH + c];
  bu[h * CH + c] = acc;
}

// ---- prep: w1^h[c'] = sum_d Wk[c',h,d] * bq[h,d] ---------------------------
__global__ void prep_w1(const float* __restrict__ Wk, const float* __restrict__ bq,
                        float* __restrict__ w1) {
  int h = blockIdx.x, cp = threadIdx.x;
  float acc = 0.f;
  for (int d = 0; d < CH; ++d)
    acc += Wk[(cp * NH + h) * CH + d] * bq[h * CH + d];
  w1[h * CH + cp] = acc;
}

// ---- T phase: T[i][c'] = sum_c X[i,c] Gt[c',c] (+w1), 2 i-half passes ------
__device__ __forceinline__ void t_phase(const bf16_t* __restrict__ gt,
                                        const float* __restrict__ w1h,
                                        const bf16_t* Xl, bf16_t* Tdst,
                                        int hh, int wm, int lane, int l15, int lg) {
  f32x4 ww[3];
#pragma unroll
  for (int mi = 0; mi < 3; ++mi)
    ww[mi] = *(const f32x4*)&w1h[(wm + mi) * 16 + lg * 4];
#pragma unroll
  for (int ip = 0; ip < 2; ++ip) {
    f32x4 acc[3][2];
#pragma unroll
    for (int mi = 0; mi < 3; ++mi)
#pragma unroll
      for (int n2 = 0; n2 < 2; ++n2) acc[mi][n2] = ww[mi];
#pragma unroll
    for (int ks = 0; ks < 6; ++ks) {
      bf16x8 af[3], bfr[2];
#pragma unroll
      for (int mi = 0; mi < 3; ++mi)
        af[mi] = *(const bf16x8*)&gt[((((hh * 12 + wm + mi) * 6 + ks) << 6) + lane) * 8];
#pragma unroll
      for (int n2 = 0; n2 < 2; ++n2)
        bfr[n2] = *(const bf16x8*)&Xl[((ip * 2 + n2) * 16 + l15) * XLD + ks * 32 + lg * 8];
#pragma unroll
      for (int mi = 0; mi < 3; ++mi)
#pragma unroll
        for (int n2 = 0; n2 < 2; ++n2)
          acc[mi][n2] = __builtin_amdgcn_mfma_f32_16x16x32_bf16(af[mi], bfr[n2], acc[mi][n2], 0, 0, 0);
    }
#pragma unroll
    for (int mi = 0; mi < 3; ++mi) {
      int cp0 = (wm + mi) * 16 + lg * 4;
#pragma unroll
      for (int n2 = 0; n2 < 2; ++n2) {
        int i = (ip * 2 + n2) * 16 + l15;
        if (i < 49) {
          bf16x4 pk = { (bf16_t)acc[mi][n2][0], (bf16_t)acc[mi][n2][1],
                        (bf16_t)acc[mi][n2][2], (bf16_t)acc[mi][n2][3] };
          *(bf16x4*)&Tdst[i * XLD + cp0] = pk;
        }
      }
    }
  }
}

// ---- fused swin block: one 4-wave workgroup per window, 1 barrier/head -----
__global__ __launch_bounds__(256, 2) void swin_fused(
    const float* __restrict__ x,
    const float* __restrict__ bo,
    const bf16_t* __restrict__ wts,     // Gt | U (both swizzled)
    const float* __restrict__ bu, const float* __restrict__ w1,
    float* __restrict__ out) {
  extern __shared__ char smem_raw[];
  bf16_t* lds = (bf16_t*)smem_raw;
  bf16_t* Xl  = lds + X_OFF;

  const int tid  = threadIdx.x;
  const int wave = tid >> 6;           // 0..3  (owns i-tile `wave`)
  const int lane = tid & 63;
  const int l15  = lane & 15;
  const int lg   = lane >> 4;          // 0..3

  const int blk = blockIdx.x;
  const int b   = blk >> 8;
  const int rem = blk & 255;
  const int wi  = rem >> 4, wj = rem & 15;

  // stage window tokens (roll -3,-3 folded into the gather), f32 -> bf16.
  // Only rows < 49 exist; all consumers mask/guard rows >= 49.
  for (int idx = tid; idx < 49 * 48; idx += 256) {
    int t = idx / 48, q4 = idx % 48;
    int hs = wi * 7 + t / 7 + SHIFT; if (hs >= HW) hs -= HW;
    int ws2 = wj * 7 + t % 7 + SHIFT; if (ws2 >= HW) ws2 -= HW;
    const float4 v = *(const float4*)&x[(((b * HW + hs) * HW) + ws2) * CH + q4 * 4];
    bf16x4 pk = { (bf16_t)v.x, (bf16_t)v.y, (bf16_t)v.z, (bf16_t)v.w };
    *(bf16x4*)&Xl[t * XLD + q4 * 4] = pk;
  }
  __syncthreads();   // X ready

  const int wm = wave * 3;             // 3 c'/c-tiles owned per wave
  const float scale = 0.07216878364870322f;  // 1/sqrt(192)

  // prologue: T(0) -> T0
  t_phase(wts, w1, Xl, lds + T0_OFF, 0, wm, lane, l15, lg);
  __syncthreads();   // T(0) ready

  f32x4 yacc[3][4] = {};               // lane: Y[t=ni*16+lg*4+r][c=(wm+mi)*16+l15]

  for (int h = 0; h < NH; ++h) {
    const bf16_t* Tcur = lds + ((h & 1) ? T1_OFF : T0_OFF);
    bf16_t*       Pcur = lds + ((h & 1) ? P1_OFF : P0_OFF);

    // ---- S(h): S[i = wave-tile, j] = sum_c' X[j,c'] T[i,c'].
    // Softmax WITHOUT max-pass: scores are tiny by construction (|s*scale|
    // std ~0.08, exp in [0.7,1.4]) -> P = e_j / sum e_j exactly.
    bf16x4 psave[4];
    {
      f32x4 sacc[4] = {};
#pragma unroll
      for (int ks = 0; ks < 6; ++ks) {
        bf16x8 bt = *(const bf16x8*)&Tcur[(wave * 16 + l15) * XLD + ks * 32 + lg * 8];
#pragma unroll
        for (int mj = 0; mj < 4; ++mj) {
          bf16x8 af = *(const bf16x8*)&Xl[(mj * 16 + l15) * XLD + ks * 32 + lg * 8];
          sacc[mj] = __builtin_amdgcn_mfma_f32_16x16x32_bf16(af, bt, sacc[mj], 0, 0, 0);
        }
      }
      float p[4][4];
      float sum = 0.f;
#pragma unroll
      for (int mj = 0; mj < 3; ++mj)
#pragma unroll
        for (int r = 0; r < 4; ++r) {
          float e = __expf(sacc[mj][r] * scale);
          p[mj][r] = e;
          sum += e;
        }
      {  // mj==3: only j==48 (lg==0, r==0) is a real row
        float e0 = (lg == 0) ? __expf(sacc[3][0] * scale) : 0.f;
        p[3][0] = e0; p[3][1] = 0.f; p[3][2] = 0.f; p[3][3] = 0.f;
        sum += e0;
      }
      sum += __shfl_xor(sum, 16);
      sum += __shfl_xor(sum, 32);
      float inv = 1.f / sum;
#pragma unroll
      for (int mj = 0; mj < 4; ++mj) {
        bf16x4 pk = { (bf16_t)(p[mj][0] * inv), (bf16_t)(p[mj][1] * inv),
                      (bf16_t)(p[mj][2] * inv), (bf16_t)(p[mj][3] * inv) };
        psave[mj] = pk;
      }
    }
    // ---- P-write(h): P[i][j] rows into Pcur (read by Y after the barrier)
    {
      int irow = wave * 16 + l15;
#pragma unroll
      for (int mj = 0; mj < 4; ++mj)
        *(bf16x4*)&Pcur[irow * PLD + mj * 16 + lg * 4] = psave[mj];
    }
    // ---- T(h+1) into the other T buffer (hazard-free: S read Tcur, B1 ahead)
    if (h + 1 < NH)
      t_phase(wts, w1 + (h + 1) * CH, Xl, lds + (((h + 1) & 1) ? T1_OFF : T0_OFF),
              h + 1, wm, lane, l15, lg);
    // ---- VO(h): VO[c][s] = sum_cin X[s,cin] U[c,cin] (+bu), kept in regs.
    // Per-mi pass; vacc lane layout (c = l15 fixed, s in regs) IS the Y B-frag.
    bf16x8 bfrag[3][2];
    {
      const bf16_t* U_w = wts + U_OFF_ELEMS;
      const float* bu_h = bu + h * CH;
#pragma unroll
      for (int mi = 0; mi < 3; ++mi) {
        const f32x4 bbv = *(const f32x4*)&bu_h[(wm + mi) * 16 + lg * 4];
        f32x4 vacc[4];
#pragma unroll
        for (int ms = 0; ms < 4; ++ms) vacc[ms] = bbv;
#pragma unroll
        for (int ks = 0; ks < 6; ++ks) {
          bf16x8 bfu = *(const bf16x8*)&U_w[((((h * 12 + wm + mi) * 6 + ks) << 6) + lane) * 8];
#pragma unroll
          for (int ms = 0; ms < 4; ++ms) {
            bf16x8 af = *(const bf16x8*)&Xl[(ms * 16 + l15) * XLD + ks * 32 + lg * 8];
            vacc[ms] = __builtin_amdgcn_mfma_f32_16x16x32_bf16(af, bfu, vacc[ms], 0, 0, 0);
          }
        }
        // zero garbage s >= 49 slots (X rows 49-63 are unstaged garbage)
        if (lg) { vacc[3] = (f32x4){0.f, 0.f, 0.f, 0.f}; }
        else    { vacc[3][1] = 0.f; vacc[3][2] = 0.f; vacc[3][3] = 0.f; }
#pragma unroll
        for (int kp = 0; kp < 2; ++kp) {
          bf16x4 lo = { (bf16_t)vacc[2 * kp][0], (bf16_t)vacc[2 * kp][1],
                        (bf16_t)vacc[2 * kp][2], (bf16_t)vacc[2 * kp][3] };
          bf16x4 hi = { (bf16_t)vacc[2 * kp + 1][0], (bf16_t)vacc[2 * kp + 1][1],
                        (bf16_t)vacc[2 * kp + 1][2], (bf16_t)vacc[2 * kp + 1][3] };
          bfrag[mi][kp] = __builtin_shufflevector(lo, hi, 0, 1, 2, 3, 4, 5, 6, 7);
        }
      }
    }
    __syncthreads();   // B1(h): all waves' P(h) and T(h+1) written
    // ---- Y(h): Y[t][c] += sum_s P[t,s] VO[c,s].
    // A = P rows (permuted b64 pair, k~ = s); B = bfrag (same permutation).
    {
#pragma unroll
      for (int ni = 0; ni < 4; ++ni) {
#pragma unroll
        for (int kp = 0; kp < 2; ++kp) {
          const bf16_t* pr = &Pcur[(ni * 16 + l15) * PLD + kp * 32 + lg * 4];
          bf16x4 a0 = *(const bf16x4*)pr;
          bf16x4 a1 = *(const bf16x4*)(pr + 16);
          bf16x8 af8 = __builtin_shufflevector(a0, a1, 0, 1, 2, 3, 4, 5, 6, 7);
#pragma unroll
          for (int mi = 0; mi < 3; ++mi)
            yacc[mi][ni] = __builtin_amdgcn_mfma_f32_16x16x32_bf16(af8, bfrag[mi][kp], yacc[mi][ni], 0, 0, 0);
        }
      }
    }
    // no trailing barrier: next iteration's writes touch only the other
    // T/P buffers; all cross-buffer hazards were separated by B1(h).
  }

  // ---- epilogue: +bo, plain-reshape merge + roll(+3,+3), scalar f32 stores
  {
    float bov[3];
#pragma unroll
    for (int mi = 0; mi < 3; ++mi) bov[mi] = bo[(wm + mi) * 16 + l15];
#pragma unroll
    for (int ni = 0; ni < 4; ++ni) {
#pragma unroll
      for (int r = 0; r < 4; ++r) {
        int t = ni * 16 + lg * 4 + r;
        if (t < 49) {
          int pos = rem * 49 + t;
          int hp = pos / 112, wp = pos % 112;
          hp += SHIFT; if (hp >= HW) hp -= HW;
          wp += SHIFT; if (wp >= HW) wp -= HW;
          float* op = out + (((b * HW + hp) * HW) + wp) * CH + l15;
#pragma unroll
          for (int mi = 0; mi < 3; ++mi)
            op[(wm + mi) * 16] = yacc[mi][ni][r] + bov[mi];
        }
      }
    }
  }
}

extern "C" void kernel_launch(void* const* d_in, const int* in_sizes, int n_in,
                              void* d_out, int out_size, void* d_ws, size_t ws_size,
                              hipStream_t stream) {
  const float* x  = (const float*)d_in[0];
  const float* Wq = (const float*)d_in[1];
  const float* bq = (const float*)d_in[2];
  const float* Wk = (const float*)d_in[3];
  const float* Wv = (const float*)d_in[5];
  const float* bv = (const float*)d_in[6];
  const float* Wo = (const float*)d_in[7];
  const float* bo = (const float*)d_in[8];
  float* out = (float*)d_out;
  bf16_t* wts = (bf16_t*)d_ws;                        // Gt | U, swizzled
  float*  bu  = (float*)((char*)d_ws + BU_OFF_BYTES);
  float*  w1  = (float*)((char*)d_ws + W1_OFF_BYTES);

  prep_gt<<<NH * CH, CH, 0, stream>>>(Wq, Wk, wts);
  prep_u<<<NH * CH, CH, 0, stream>>>(Wv, Wo, wts + U_OFF_ELEMS);
  prep_bu<<<NH, CH, 0, stream>>>(bv, Wo, bu);
  prep_w1<<<NH, CH, 0, stream>>>(Wk, bq, w1);

  (void)hipFuncSetAttribute((const void*)swin_fused,
                            hipFuncAttributeMaxDynamicSharedMemorySize, LDS_BYTES);
  swin_fused<<<dim3(4096), dim3(256), LDS_BYTES, stream>>>(x, bo, wts, bu, w1, out);
}